// Round 4
// baseline (487.480 us; speedup 1.0000x reference)
//
#include <hip/hip_runtime.h>

// Problem constants (fixed by reference): B=4, C=64, H=W=64 -> N=4096
#define NN 4096
#define CD 64

typedef __attribute__((ext_vector_type(8))) short bf16x8; // 8 bf16 in 4 VGPRs
typedef __attribute__((ext_vector_type(4))) float f32x4;

// Device-global workspace (~75 MB), fully rewritten each launch.
__device__ unsigned short g_Qh[2][4][NN][CD]; // Q^T hi  [n][c], c contiguous
__device__ unsigned short g_Ql[2][4][NN][CD]; // Q^T lo
__device__ unsigned short g_Kh[2][4][NN][CD]; // K^T hi
__device__ unsigned short g_Kl[2][4][NN][CD]; // K^T lo
__device__ float          g_Vf[2][4][CD][NN]; // V fp32 (pre-fold)
__device__ unsigned short g_Vh[2][4][CD][NN]; // V*g/Z hi
__device__ unsigned short g_Vl[2][4][CD][NN]; // V*g/Z lo
__device__ float          g_Op[4][2][4][CD][NN]; // partial attn out (i-split)
__device__ float          g_Zp[4][2][4][NN];     // partial softmax denoms (j-split)

__device__ inline f32x4 mfma16(bf16x8 a, bf16x8 b, f32x4 c) {
  return __builtin_amdgcn_mfma_f32_16x16x32_bf16(a, b, c, 0, 0, 0);
}

// Truncation hi + RNE lo split: x ~= hi + lo, |x-(hi+lo)| <= 2^-17 |x|
__device__ inline void split_bf(float x, unsigned short& h, unsigned short& l) {
  unsigned u = __builtin_bit_cast(unsigned, x);
  h = (unsigned short)(u >> 16);
  float hf = __builtin_bit_cast(float, u & 0xffff0000u);
  unsigned v = __builtin_bit_cast(unsigned, x - hf);
  v += 0x7fffu + ((v >> 16) & 1u);
  l = (unsigned short)(v >> 16);
}

// Raw barrier: drain LDS ops only; global prefetches stay in flight (T4).
__device__ inline void lds_barrier() {
  asm volatile("s_waitcnt lgkmcnt(0)\n\ts_barrier" ::: "memory");
}

struct ProjArgs {
  const float* x;
  const float* W[6];
  const float* bias[6];
};

// ---------------------------------------------------------------------------
// Kernel 1: six 1x1-conv projections, fp32 compute.
// Q/K written transposed ([n][c], c contiguous) split into bf16 hi/lo.
// V written fp32 [c][n] (hi/lo split happens after the 1/Z fold).
// ---------------------------------------------------------------------------
__global__ __launch_bounds__(256) void proj_kernel(ProjArgs a) {
  __shared__ float Wt[64][68];
  __shared__ float bs[64];
  const int tid = threadIdx.x;
  const int m = blockIdx.z; // 0..5 = qh,kh,vh,ql,kl,vl
  const float* __restrict__ W = a.W[m];
#pragma unroll
  for (int k = 0; k < 16; ++k) {
    int t = k * 256 + tid; // t = o*64 + c
    Wt[t & 63][t >> 6] = W[t];
  }
  if (tid < 64) bs[tid] = a.bias[m][tid];
  __syncthreads();

  const int b = blockIdx.y;
  const int n = (blockIdx.x << 6) + (tid & 63);
  const int og = tid >> 6;
  const float* __restrict__ xp = a.x + ((size_t)b * CD) * NN + n;

  float acc[16];
#pragma unroll
  for (int k = 0; k < 16; ++k) acc[k] = bs[og * 16 + k];

#pragma unroll 4
  for (int c = 0; c < 64; ++c) {
    float xv = xp[(size_t)c * NN];
    float w[16];
    *(float4*)&w[0]  = *(const float4*)&Wt[c][og * 16 + 0];
    *(float4*)&w[4]  = *(const float4*)&Wt[c][og * 16 + 4];
    *(float4*)&w[8]  = *(const float4*)&Wt[c][og * 16 + 8];
    *(float4*)&w[12] = *(const float4*)&Wt[c][og * 16 + 12];
#pragma unroll
    for (int k = 0; k < 16; ++k) acc[k] += w[k] * xv;
  }

  const int br = m / 3, kind = m % 3;
  if (kind == 2) { // V: fp32 [c][n]
    float* dst = &g_Vf[br][b][0][0] + n;
#pragma unroll
    for (int k = 0; k < 16; ++k) dst[(size_t)(og * 16 + k) * NN] = acc[k];
  } else { // Q/K: bf16 hi/lo, transposed [n][c]
    unsigned short hi[16], lo[16];
#pragma unroll
    for (int k = 0; k < 16; ++k) split_bf(acc[k], hi[k], lo[k]);
    unsigned short* dh = (kind == 0) ? &g_Qh[br][b][n][og * 16] : &g_Kh[br][b][n][og * 16];
    unsigned short* dl = (kind == 0) ? &g_Ql[br][b][n][og * 16] : &g_Kl[br][b][n][og * 16];
    *(uint4*)dh       = *(const uint4*)&hi[0];
    *(uint4*)(dh + 8) = *(const uint4*)&hi[8];
    *(uint4*)dl       = *(const uint4*)&lo[0];
    *(uint4*)(dl + 8) = *(const uint4*)&lo[8];
  }
}

// ---------------------------------------------------------------------------
// Kernel 2: pass 1 — Zp[js][i] = sum_{j in js-range} exp(S[i,j]).
// grid 2048 (bid&7=image -> XCD pin, (bid>>3)&3 = j-split, bid>>5 = i-block).
// LDS-free t-loop: B-frags (K^T) loaded straight from global (L2-resident);
// waves fully independent until the tiny zbuf combine at the end.
// ---------------------------------------------------------------------------
__global__ __launch_bounds__(256) void pass1_kernel() {
  __shared__ float zbuf[2][64];

  const int tid = threadIdx.x;
  const int bid = blockIdx.x;
  const int img = bid & 7;
  const int br = img >> 2, b = img & 3;
  const int js = (bid >> 3) & 3;
  const int i0 = (bid >> 5) << 6;

  const int lane = tid & 63, w = tid >> 6;
  const int wi = w >> 1, wj = w & 1;
  const int lm = lane & 15, q = lane >> 4;

  const unsigned short* __restrict__ QhB = &g_Qh[br][b][0][0];
  const unsigned short* __restrict__ QlB = &g_Ql[br][b][0][0];
  const unsigned short* __restrict__ KhB = &g_Kh[br][b][0][0];
  const unsigned short* __restrict__ KlB = &g_Kl[br][b][0][0];

  // Static A-frags (Q): [it][cstep][hi/lo]
  bf16x8 qa[2][2][2];
#pragma unroll
  for (int it = 0; it < 2; ++it)
#pragma unroll
    for (int cs = 0; cs < 2; ++cs) {
      size_t off = (size_t)(i0 + wi * 32 + it * 16 + lm) * 64 + cs * 32 + q * 8;
      qa[it][cs][0] = *(const bf16x8*)(QhB + off);
      qa[it][cs][1] = *(const bf16x8*)(QlB + off);
    }

  float zacc[2][4];
#pragma unroll
  for (int it = 0; it < 2; ++it)
#pragma unroll
    for (int r = 0; r < 4; ++r) zacc[it][r] = 0.f;

  const int jwave = wj * 32 + lm; // row-within-tile for this lane
  for (int tt = 0; tt < 16; ++tt) {
    const int jb = ((js << 4) + tt) << 6;

    bf16x8 kb[2][2][2]; // [jt][cstep][hi/lo] straight from global
#pragma unroll
    for (int jt = 0; jt < 2; ++jt) {
      size_t rowo = (size_t)(jb + jwave + jt * 16) * 64 + q * 8;
#pragma unroll
      for (int cs = 0; cs < 2; ++cs) {
        kb[jt][cs][0] = *(const bf16x8*)(KhB + rowo + cs * 32);
        kb[jt][cs][1] = *(const bf16x8*)(KlB + rowo + cs * 32);
      }
    }

    const f32x4 zf = {0.f, 0.f, 0.f, 0.f};
#pragma unroll
    for (int it = 0; it < 2; ++it)
#pragma unroll
      for (int jt = 0; jt < 2; ++jt) {
        f32x4 s = mfma16(qa[it][0][0], kb[jt][0][0], zf);
        s = mfma16(qa[it][1][0], kb[jt][1][0], s);
        s = mfma16(qa[it][0][0], kb[jt][0][1], s);
        s = mfma16(qa[it][1][0], kb[jt][1][1], s);
        s = mfma16(qa[it][0][1], kb[jt][0][0], s);
        s = mfma16(qa[it][1][1], kb[jt][1][0], s);
        zacc[it][0] += __expf(s[0]);
        zacc[it][1] += __expf(s[1]);
        zacc[it][2] += __expf(s[2]);
        zacc[it][3] += __expf(s[3]);
      }
  }

#pragma unroll
  for (int mm = 1; mm < 16; mm <<= 1)
#pragma unroll
    for (int it = 0; it < 2; ++it)
#pragma unroll
      for (int r = 0; r < 4; ++r) zacc[it][r] += __shfl_xor(zacc[it][r], mm, 64);

  if (lm == 0) {
#pragma unroll
    for (int it = 0; it < 2; ++it)
#pragma unroll
      for (int r = 0; r < 4; ++r)
        zbuf[wj][wi * 32 + it * 16 + q * 4 + r] = zacc[it][r];
  }
  __syncthreads();
  if (tid < 64) g_Zp[js][br][b][i0 + tid] = zbuf[0][tid] + zbuf[1][tid];
}

// ---------------------------------------------------------------------------
// Kernel 3: Z = sum of 4 partials; fold g/Z into V; split into bf16 hi/lo.
// ---------------------------------------------------------------------------
__global__ __launch_bounds__(256) void scalev_kernel(const float* __restrict__ g1,
                                                     const float* __restrict__ g2) {
  int idx = blockIdx.x * 256 + threadIdx.x; // 2*4*64*1024 float4 chunks
  int i4 = idx & 1023;
  int c  = (idx >> 10) & 63;
  int b  = (idx >> 16) & 3;
  int br = idx >> 18;
  float g = br ? g2[0] : g1[0];
  float4 z0 = *(const float4*)&g_Zp[0][br][b][i4 * 4];
  float4 z1 = *(const float4*)&g_Zp[1][br][b][i4 * 4];
  float4 z2 = *(const float4*)&g_Zp[2][br][b][i4 * 4];
  float4 z3 = *(const float4*)&g_Zp[3][br][b][i4 * 4];
  float4 z = {z0.x + z1.x + z2.x + z3.x, z0.y + z1.y + z2.y + z3.y,
              z0.z + z1.z + z2.z + z3.z, z0.w + z1.w + z2.w + z3.w};
  float4 v = *(const float4*)&g_Vf[br][b][c][i4 * 4];
  float vv[4] = {v.x * g / z.x, v.y * g / z.y, v.z * g / z.z, v.w * g / z.w};
  unsigned short h[4], l[4];
#pragma unroll
  for (int r = 0; r < 4; ++r) split_bf(vv[r], h[r], l[r]);
  uint2 uh, ul;
  uh.x = (unsigned)h[0] | ((unsigned)h[1] << 16);
  uh.y = (unsigned)h[2] | ((unsigned)h[3] << 16);
  ul.x = (unsigned)l[0] | ((unsigned)l[1] << 16);
  ul.y = (unsigned)l[2] | ((unsigned)l[3] << 16);
  *(uint2*)&g_Vh[br][b][c][i4 * 4] = uh;
  *(uint2*)&g_Vl[br][b][c][i4 * 4] = ul;
}

// ---------------------------------------------------------------------------
// Kernel 4: pass 2 — Op[is][c,j] = sum_{i in is-range} Vn[c,i]*exp(S[i,j]).
// grid 2048 (bid&7=image, (bid>>3)&3 = i-split, bid>>5 = j-block).
// Kt-frags static in regs; Q/V frags direct from global (L2) issue-early;
// P staged via 16 KiB swizzled LDS (cross-wave wi<->wj exchange).
// ---------------------------------------------------------------------------
__global__ __launch_bounds__(256, 2) void pass2_kernel() {
  __shared__ unsigned short pt_h[64 * 64]; // [j][i] swizzled
  __shared__ unsigned short pt_l[64 * 64];

  const int tid = threadIdx.x;
  const int bid = blockIdx.x;
  const int img = bid & 7;
  const int br = img >> 2, b = img & 3;
  const int is = (bid >> 3) & 3;
  const int j0 = (bid >> 5) << 6;

  const int lane = tid & 63, w = tid >> 6;
  const int wi = w >> 1, wj = w & 1; // wi: i-sub(S)/c-sub(PV); wj: j-sub
  const int lm = lane & 15, q = lane >> 4;

  const unsigned short* __restrict__ QhB = &g_Qh[br][b][0][0];
  const unsigned short* __restrict__ QlB = &g_Ql[br][b][0][0];
  const unsigned short* __restrict__ KhB = &g_Kh[br][b][0][0];
  const unsigned short* __restrict__ KlB = &g_Kl[br][b][0][0];
  const unsigned short* __restrict__ VhB = &g_Vh[br][b][0][0];
  const unsigned short* __restrict__ VlB = &g_Vl[br][b][0][0];

  // Static B-frags (Kt) for this block's j-columns: [jt][cstep][hi/lo]
  bf16x8 kb[2][2][2];
#pragma unroll
  for (int jt = 0; jt < 2; ++jt)
#pragma unroll
    for (int cs = 0; cs < 2; ++cs) {
      size_t off = (size_t)(j0 + wj * 32 + jt * 16 + lm) * 64 + cs * 32 + q * 8;
      kb[jt][cs][0] = *(const bf16x8*)(KhB + off);
      kb[jt][cs][1] = *(const bf16x8*)(KlB + off);
    }

  bf16x8 qa[2][2][2]; // [it][cstep][hi/lo]
  bf16x8 va[2][2][2]; // [ct][kstep][hi/lo]
  auto loadQ = [&](int ib) {
#pragma unroll
    for (int it = 0; it < 2; ++it)
#pragma unroll
      for (int cs = 0; cs < 2; ++cs) {
        size_t off = (size_t)(ib + wi * 32 + it * 16 + lm) * 64 + cs * 32 + q * 8;
        qa[it][cs][0] = *(const bf16x8*)(QhB + off);
        qa[it][cs][1] = *(const bf16x8*)(QlB + off);
      }
  };
  auto loadV = [&](int ib) {
#pragma unroll
    for (int ct = 0; ct < 2; ++ct)
#pragma unroll
      for (int ks = 0; ks < 2; ++ks) {
        size_t off = (size_t)(wi * 32 + ct * 16 + lm) * NN + ib + ks * 32 + q * 8;
        va[ct][ks][0] = *(const bf16x8*)(VhB + off);
        va[ct][ks][1] = *(const bf16x8*)(VlB + off);
      }
  };
  const int ibase = is << 10; // this block's 1024-i range
  loadQ(ibase);
  loadV(ibase);

  f32x4 oacc[2][2];
#pragma unroll
  for (int ct = 0; ct < 2; ++ct)
#pragma unroll
    for (int jt = 0; jt < 2; ++jt) oacc[ct][jt] = (f32x4){0.f, 0.f, 0.f, 0.f};

  for (int tt = 0; tt < 16; ++tt) {
    const int inext = ibase + ((tt + 1) << 6);
    // ---- S phase ----
    const f32x4 zf = {0.f, 0.f, 0.f, 0.f};
    f32x4 sacc[2][2];
#pragma unroll
    for (int it = 0; it < 2; ++it)
#pragma unroll
      for (int jt = 0; jt < 2; ++jt) {
        f32x4 s = mfma16(qa[it][0][0], kb[jt][0][0], zf);
        s = mfma16(qa[it][1][0], kb[jt][1][0], s);
        s = mfma16(qa[it][0][0], kb[jt][0][1], s);
        s = mfma16(qa[it][1][0], kb[jt][1][1], s);
        s = mfma16(qa[it][0][1], kb[jt][0][0], s);
        s = mfma16(qa[it][1][1], kb[jt][1][0], s);
        sacc[it][jt] = s;
      }
    if (tt < 15) loadQ(inext); // issue-early; waited at next iter's S

    // exp + hi/lo split + pack (into regs, before barrier)
    uint2 wh[2][2], wl[2][2];
#pragma unroll
    for (int it = 0; it < 2; ++it)
#pragma unroll
      for (int jt = 0; jt < 2; ++jt) {
        unsigned short h[4], l[4];
#pragma unroll
        for (int r = 0; r < 4; ++r) {
          float e = __expf(sacc[it][jt][r]);
          split_bf(e, h[r], l[r]);
        }
        wh[it][jt].x = (unsigned)h[0] | ((unsigned)h[1] << 16);
        wh[it][jt].y = (unsigned)h[2] | ((unsigned)h[3] << 16);
        wl[it][jt].x = (unsigned)l[0] | ((unsigned)l[1] << 16);
        wl[it][jt].y = (unsigned)l[2] | ((unsigned)l[3] << 16);
      }

    lds_barrier(); // A: previous PV reads of Pt complete
#pragma unroll
    for (int it = 0; it < 2; ++it)
#pragma unroll
      for (int jt = 0; jt < 2; ++jt) {
        int row = wj * 32 + jt * 16 + lm;
        int byte = row * 128 + (((wi * 64) + it * 32 + q * 8) ^ ((row & 7) << 4));
        *(uint2*)((char*)pt_h + byte) = wh[it][jt];
        *(uint2*)((char*)pt_l + byte) = wl[it][jt];
      }
    lds_barrier(); // B: Pt(t) visible

    // ---- PV phase ----
    bf16x8 pb[2][2][2]; // [jt][kstep][hi/lo]
#pragma unroll
    for (int jt = 0; jt < 2; ++jt) {
      int row = wj * 32 + jt * 16 + lm;
      int rb = row * 128, sw = (row & 7) << 4;
#pragma unroll
      for (int ks = 0; ks < 2; ++ks) {
        int byte = rb + ((ks * 64 + q * 16) ^ sw);
        pb[jt][ks][0] = *(const bf16x8*)((const char*)pt_h + byte);
        pb[jt][ks][1] = *(const bf16x8*)((const char*)pt_l + byte);
      }
    }
#pragma unroll
    for (int ct = 0; ct < 2; ++ct)
#pragma unroll
      for (int jt = 0; jt < 2; ++jt) {
        f32x4 o = oacc[ct][jt];
        o = mfma16(va[ct][0][0], pb[jt][0][0], o); // Vh*Ph k0
        o = mfma16(va[ct][1][0], pb[jt][1][0], o); // Vh*Ph k1
        o = mfma16(va[ct][0][0], pb[jt][0][1], o); // Vh*Pl k0
        o = mfma16(va[ct][1][0], pb[jt][1][1], o); // Vh*Pl k1
        o = mfma16(va[ct][0][1], pb[jt][0][0], o); // Vl*Ph k0
        o = mfma16(va[ct][1][1], pb[jt][1][0], o); // Vl*Ph k1
        oacc[ct][jt] = o;
      }
    if (tt < 15) loadV(inext); // issue-early; waited at next iter's PV
  }

  float* __restrict__ Ob = &g_Op[is][br][b][0][0];
#pragma unroll
  for (int ct = 0; ct < 2; ++ct)
#pragma unroll
    for (int jt = 0; jt < 2; ++jt)
#pragma unroll
      for (int r = 0; r < 4; ++r)
        Ob[(size_t)(wi * 32 + ct * 16 + q * 4 + r) * NN + j0 + wj * 32 + jt * 16 + lm] =
            oacc[ct][jt][r];
}

// ---------------------------------------------------------------------------
// Kernel 5: final 1x1 conv over concat, summing the 4 i-split partials first.
// ---------------------------------------------------------------------------
__global__ __launch_bounds__(256) void final_kernel(const float* __restrict__ Wf,
                                                    const float* __restrict__ bf,
                                                    float* __restrict__ out) {
  __shared__ float Wt[128][68];
  __shared__ float bs[64];
  const int tid = threadIdx.x;
#pragma unroll
  for (int k = 0; k < 32; ++k) {
    int t = k * 256 + tid; // t = o*128 + c'
    Wt[t & 127][t >> 7] = Wf[t];
  }
  if (tid < 64) bs[tid] = bf[tid];
  __syncthreads();

  const int b = blockIdx.y;
  const int n = (blockIdx.x << 6) + (tid & 63);
  const int og = tid >> 6;
  const size_t PS = (size_t)2 * 4 * CD * NN; // stride between partials

  float acc[16];
#pragma unroll
  for (int k = 0; k < 16; ++k) acc[k] = bs[og * 16 + k];

#pragma unroll
  for (int br = 0; br < 2; ++br) {
    const float* __restrict__ Ob = &g_Op[0][br][b][0][0];
#pragma unroll 4
    for (int c = 0; c < 64; ++c) {
      const float* p = Ob + (size_t)c * NN + n;
      float xv = p[0] + p[PS] + p[2 * PS] + p[3 * PS];
      float wv[16];
      *(float4*)&wv[0]  = *(const float4*)&Wt[br * 64 + c][og * 16 + 0];
      *(float4*)&wv[4]  = *(const float4*)&Wt[br * 64 + c][og * 16 + 4];
      *(float4*)&wv[8]  = *(const float4*)&Wt[br * 64 + c][og * 16 + 8];
      *(float4*)&wv[12] = *(const float4*)&Wt[br * 64 + c][og * 16 + 12];
#pragma unroll
      for (int k = 0; k < 16; ++k) acc[k] += wv[k] * xv;
    }
  }

  float* op = out + ((size_t)b * CD) * NN + n;
#pragma unroll
  for (int k = 0; k < 16; ++k) op[(size_t)(og * 16 + k) * NN] = acc[k];
}

// ---------------------------------------------------------------------------
extern "C" void kernel_launch(void* const* d_in, const int* in_sizes, int n_in,
                              void* d_out, int out_size, void* d_ws, size_t ws_size,
                              hipStream_t stream) {
  (void)in_sizes; (void)n_in; (void)d_ws; (void)ws_size; (void)out_size;

  ProjArgs pa;
  pa.x = (const float*)d_in[0];
  for (int m = 0; m < 6; ++m) {
    pa.W[m]    = (const float*)d_in[1 + 2 * m];
    pa.bias[m] = (const float*)d_in[2 + 2 * m];
  }
  const float* g1 = (const float*)d_in[13];
  const float* g2 = (const float*)d_in[14];
  const float* Wf = (const float*)d_in[15];
  const float* bf = (const float*)d_in[16];
  float* out = (float*)d_out;

  proj_kernel<<<dim3(64, 4, 6), 256, 0, stream>>>(pa);
  pass1_kernel<<<dim3(2048), 256, 0, stream>>>();
  scalev_kernel<<<dim3(2048), 256, 0, stream>>>(g1, g2);
  pass2_kernel<<<dim3(2048), 256, 0, stream>>>();
  final_kernel<<<dim3(64, 4), 256, 0, stream>>>(Wf, bf, out);
}